// Round 7
// baseline (393.634 us; speedup 1.0000x reference)
//
#include <hip/hip_runtime.h>
#include <math.h>

#define HID 2048
#define TOKENS 4096   // B*T
#define TT 2048       // T
#define NCH 4096      // B*HID independent scan channels
#define NC 32         // scan chunks along T
#define CL 64         // chunk length = TT/NC
#define WELEM 4194304 // 2048*2048

typedef unsigned short u16;
typedef signed char i8;
typedef int i32x4 __attribute__((ext_vector_type(4)));

__device__ inline float sigm(float x) { return 1.0f / (1.0f + expf(-x)); }

__device__ inline float wred_sum(float v) {
#pragma unroll
  for (int o = 32; o > 0; o >>= 1) v += __shfl_down(v, o);
  return v;
}
__device__ inline float wred_max(float v) {
#pragma unroll
  for (int o = 32; o > 0; o >>= 1) v = fmaxf(v, __shfl_down(v, o));
  return v;
}
__device__ inline double wred_sumd(double v) {
#pragma unroll
  for (int o = 32; o > 0; o >>= 1) v += __shfl_down(v, o);
  return v;
}

__device__ __forceinline__ int pack8(const int* qi) {
  return (qi[0] & 255) | ((qi[1] & 255) << 8) | ((qi[2] & 255) << 16)
       | ((qi[3] & 255) << 24);
}

// ---------------- K1: mean(|w|) for the 4 weights, f64 accumulation -------
__global__ __launch_bounds__(256) void absmean_kernel(
    const float* __restrict__ w0, const float* __restrict__ w1,
    const float* __restrict__ w2, const float* __restrict__ w3,
    double* __restrict__ wsum) {
  int widx = blockIdx.x >> 9;
  int blk = blockIdx.x & 511;
  const float* w = widx == 0 ? w0 : widx == 1 ? w1 : widx == 2 ? w2 : w3;
  size_t base = (size_t)blk * 8192;
  double acc = 0.0;
#pragma unroll
  for (int r = 0; r < 8; ++r) {
    float4 v = *(const float4*)&w[base + (size_t)(r * 256 + threadIdx.x) * 4];
    acc += (double)fabsf(v.x) + (double)fabsf(v.y) + (double)fabsf(v.z) +
           (double)fabsf(v.w);
  }
  acc = wred_sumd(acc);
  __shared__ double sh[4];
  int tid = threadIdx.x;
  if ((tid & 63) == 0) sh[tid >> 6] = acc;
  __syncthreads();
  if (tid == 0) atomicAdd(&wsum[widx], (sh[0] + sh[1]) + (sh[2] + sh[3]));
}

// ---------------- K2: ternary-quantize TWO weight matrices to int8 --------
__global__ __launch_bounds__(256) void wquant2_kernel(
    const float* __restrict__ wA, const float* __restrict__ wB,
    const double* __restrict__ wsum, int widxA, int widxB,
    i8* __restrict__ wqA, i8* __restrict__ wqB) {
  int sel = blockIdx.x >> 11;  // 0: A, 1: B
  int blk = blockIdx.x & 2047;
  const float* w = sel ? wB : wA;
  i8* wq = sel ? wqB : wqA;
  int widx = sel ? widxB : widxA;
  double mean = wsum[widx] * (1.0 / (double)WELEM);
  float s = (float)(1.0 / fmax(mean, 1e-5));
  size_t base = (size_t)blk * 2048 + (size_t)threadIdx.x * 8;
  float4 va = *(const float4*)&w[base];
  float4 vb = *(const float4*)&w[base + 4];
  float vv[8] = {va.x, va.y, va.z, va.w, vb.x, vb.y, vb.z, vb.w};
  int qi[8];
#pragma unroll
  for (int j = 0; j < 8; ++j) {
    float q1 = rintf(vv[j] * s);
    q1 = fminf(fmaxf(q1, -1.0f), 1.0f);
    qi[j] = (int)q1;
  }
  *(int2*)&wq[base] = make_int2(pack8(qi), pack8(qi + 4));
}

// ---------------- K3: per-token RMSNorm + 8-bit fake quant -> int8 --------
__global__ __launch_bounds__(256) void rmsquant_kernel(
    const float* __restrict__ X, const float* __restrict__ nw,
    i8* __restrict__ Xq, float* __restrict__ inv_s) {
  int tok = blockIdx.x;
  int tid = threadIdx.x;
  const float* xrow = X + (size_t)tok * HID;
  int c0 = tid * 8;
  float x[8];
  *(float4*)&x[0] = *(const float4*)&xrow[c0];
  *(float4*)&x[4] = *(const float4*)&xrow[c0 + 4];
  float ss = 0.0f;
#pragma unroll
  for (int j = 0; j < 8; ++j) ss += x[j] * x[j];
  __shared__ float sh[4];
  float v = wred_sum(ss);
  if ((tid & 63) == 0) sh[tid >> 6] = v;
  __syncthreads();
  float tot = (sh[0] + sh[1]) + (sh[2] + sh[3]);
  float rstd = (float)(1.0 / sqrt((double)(tot * (1.0f / HID)) + 1e-8));
  float y[8];
  float amax = 0.0f;
#pragma unroll
  for (int j = 0; j < 8; ++j) {
    y[j] = x[j] * rstd * nw[c0 + j];
    amax = fmaxf(amax, fabsf(y[j]));
  }
  __syncthreads();
  v = wred_max(amax);
  if ((tid & 63) == 0) sh[tid >> 6] = v;
  __syncthreads();
  float am = fmaxf(fmaxf(fmaxf(sh[0], sh[1]), fmaxf(sh[2], sh[3])), 1e-5f);
  float s = 127.0f / am;
  int qi[8];
#pragma unroll
  for (int j = 0; j < 8; ++j) {
    float qq = rintf(y[j] * s);
    qq = fminf(fmaxf(qq, -128.0f), 127.0f);
    qi[j] = (int)qq;
  }
  *(int2*)&Xq[(size_t)tok * HID + c0] = make_int2(pack8(qi), pack8(qi + 4));
  if (tid == 0) inv_s[tok] = am * (1.0f / 127.0f);
}

// ---------------- K3b: fused dual RMSNorm+quant (shares x and sum-sq) -----
__global__ __launch_bounds__(256) void rmsquant2_kernel(
    const float* __restrict__ X, const float* __restrict__ nw0,
    const float* __restrict__ nw1, i8* __restrict__ Xq0, i8* __restrict__ Xq1,
    float* __restrict__ inv0, float* __restrict__ inv1) {
  int tok = blockIdx.x;
  int tid = threadIdx.x;
  const float* xrow = X + (size_t)tok * HID;
  int c0 = tid * 8;
  float x[8];
  *(float4*)&x[0] = *(const float4*)&xrow[c0];
  *(float4*)&x[4] = *(const float4*)&xrow[c0 + 4];
  float ss = 0.0f;
#pragma unroll
  for (int j = 0; j < 8; ++j) ss += x[j] * x[j];
  __shared__ float sh[4];
  float v = wred_sum(ss);
  if ((tid & 63) == 0) sh[tid >> 6] = v;
  __syncthreads();
  float tot = (sh[0] + sh[1]) + (sh[2] + sh[3]);
  float rstd = (float)(1.0 / sqrt((double)(tot * (1.0f / HID)) + 1e-8));
#pragma unroll
  for (int pass = 0; pass < 2; ++pass) {
    const float* nw = pass == 0 ? nw0 : nw1;
    i8* Xq = pass == 0 ? Xq0 : Xq1;
    float* inv_s = pass == 0 ? inv0 : inv1;
    float y[8];
    float amax = 0.0f;
#pragma unroll
    for (int j = 0; j < 8; ++j) {
      y[j] = x[j] * rstd * nw[c0 + j];
      amax = fmaxf(amax, fabsf(y[j]));
    }
    __syncthreads();
    float vv = wred_max(amax);
    if ((tid & 63) == 0) sh[tid >> 6] = vv;
    __syncthreads();
    float am = fmaxf(fmaxf(fmaxf(sh[0], sh[1]), fmaxf(sh[2], sh[3])), 1e-5f);
    float s = 127.0f / am;
    int qi[8];
#pragma unroll
    for (int j = 0; j < 8; ++j) {
      float qq = rintf(y[j] * s);
      qq = fminf(fmaxf(qq, -128.0f), 127.0f);
      qi[j] = (int)qq;
    }
    *(int2*)&Xq[(size_t)tok * HID + c0] = make_int2(pack8(qi), pack8(qi + 4));
    if (tid == 0) inv_s[tok] = am * (1.0f / 127.0f);
  }
}

// ---------------- K4: i8 MFMA GEMM, register-direct (no LDS, no barriers) -
// out[m,n] = sum_k A[m,k]*W[n,k]; i32 accumulate (exact).
// mode 0: sigmoid(v); 1: v*sigm(v) (silu); 2: v
// Each wave owns an independent 64x64 tile (acc 4x4 of 16x16x64).
// Fragments loaded straight global->VGPR in MFMA layout: one wave
// instruction = 16 rows x 16B at 64B-aligned k -> 16 fully-used lines,
// L1/L2-served (A/W panels are L2-resident). 2-deep named-register
// prefetch, zero barriers, compiler inserts counted vmcnt.
// Grid = 512 per segment (1024 when two merged GEMMs). seg = swz>>9.
__global__ __launch_bounds__(256, 3) void gemmr_kernel(
    const i8* __restrict__ A0, const i8* __restrict__ A1,
    const i8* __restrict__ W0, const i8* __restrict__ W1,
    const float* __restrict__ inv0, const float* __restrict__ inv1,
    const double* __restrict__ wsum, int widx0, int widx1,
    float* __restrict__ O0, float* __restrict__ O1, int mode0, int mode1) {
  const int tid = threadIdx.x;
  // XCD-aware bijective swizzle (gridDim.x % 8 == 0)
  const int cpx = gridDim.x >> 3;
  const int lid = blockIdx.x;
  const int swz = (lid & 7) * cpx + (lid >> 3);
  const int seg = swz >> 9;
  const int idx = swz & 511;
  const int n0 = (idx & 15) * 128;  // 16 n-tiles (HID/128)
  const int m0 = (idx >> 4) * 128;  // 32 m-tiles (TOKENS/128)

  const i8* Aq = seg ? A1 : A0;
  const i8* Wq = seg ? W1 : W0;
  const float* inv_s = seg ? inv1 : inv0;
  float* Out = seg ? O1 : O0;
  const int mode = seg ? mode1 : mode0;
  const int widx = seg ? widx1 : widx0;

  float wscale = (float)fmax(wsum[widx] * (1.0 / (double)WELEM), 1e-5);

  const int wave = tid >> 6, lane = tid & 63;
  const int wm = wave >> 1, wn = wave & 1;  // 2x2 waves -> 128x128 block
  const int lrow = lane & 15;
  const int lk = (lane >> 4) * 16;  // k-quarter byte offset

  // per-lane fragment base pointers (row stride between frags = 16*HID)
  const i8* pA = Aq + (size_t)(m0 + wm * 64 + lrow) * HID + lk;
  const i8* pB = Wq + (size_t)(n0 + wn * 64 + lrow) * HID + lk;

  i32x4 acc[4][4];
#pragma unroll
  for (int i = 0; i < 4; ++i)
#pragma unroll
    for (int j = 0; j < 4; ++j)
#pragma unroll
      for (int r = 0; r < 4; ++r) acc[i][j][r] = 0;

  i32x4 aA0, aA1, aA2, aA3, aB0, aB1, aB2, aB3;
  i32x4 bA0, bA1, bA2, bA3, bB0, bB1, bB2, bB3;

#define LOADS(P, K0)                                   \
  P##A0 = *(const i32x4*)(pA + 0 * 16 * HID + (K0));   \
  P##A1 = *(const i32x4*)(pA + 1 * 16 * HID + (K0));   \
  P##A2 = *(const i32x4*)(pA + 2 * 16 * HID + (K0));   \
  P##A3 = *(const i32x4*)(pA + 3 * 16 * HID + (K0));   \
  P##B0 = *(const i32x4*)(pB + 0 * 16 * HID + (K0));   \
  P##B1 = *(const i32x4*)(pB + 1 * 16 * HID + (K0));   \
  P##B2 = *(const i32x4*)(pB + 2 * 16 * HID + (K0));   \
  P##B3 = *(const i32x4*)(pB + 3 * 16 * HID + (K0));

#define MFMAS(P)                                                       \
  {                                                                    \
    i32x4 _af[4] = {P##A0, P##A1, P##A2, P##A3};                       \
    i32x4 _bf[4] = {P##B0, P##B1, P##B2, P##B3};                       \
    __builtin_amdgcn_s_setprio(1);                                     \
    _Pragma("unroll") for (int i = 0; i < 4; ++i)                      \
        _Pragma("unroll") for (int j = 0; j < 4; ++j) acc[i][j] =      \
            __builtin_amdgcn_mfma_i32_16x16x64_i8(_af[i], _bf[j],      \
                                                  acc[i][j], 0, 0, 0); \
    __builtin_amdgcn_s_setprio(0);                                     \
  }

  const int NT = HID / 64;  // 32 K-steps, even
  LOADS(a, 0)
  for (int kt = 0; kt < NT; kt += 2) {
    LOADS(b, (kt + 1) * 64)
    MFMAS(a)
    if (kt + 2 < NT) LOADS(a, (kt + 2) * 64)
    MFMAS(b)
  }
#undef LOADS
#undef MFMAS

#pragma unroll
  for (int i = 0; i < 4; ++i) {
    int rbase = m0 + wm * 64 + i * 16 + (lane >> 4) * 4;
#pragma unroll
    for (int j = 0; j < 4; ++j) {
      int col = n0 + wn * 64 + j * 16 + lrow;
#pragma unroll
      for (int r = 0; r < 4; ++r) {
        int row = rbase + r;
        float v = (float)acc[i][j][r] * inv_s[row] * wscale;
        size_t oidx = (size_t)row * HID + col;
        if (mode == 0) {
          Out[oidx] = sigm(v);
        } else if (mode == 1) {
          Out[oidx] = v * sigm(v);
        } else {
          Out[oidx] = v;
        }
      }
    }
  }
}

// ---------------- K5: chunked parallel scan h = f*h + silu_i*(1-f) --------
__global__ __launch_bounds__(256) void scan1_kernel(
    const float* __restrict__ F, float* __restrict__ IO, float* __restrict__ P,
    float* __restrict__ H) {
  int c = blockIdx.x * 256 + threadIdx.x;
  int q = blockIdx.y;
  size_t base =
      (size_t)(c >> 11) * TT * HID + (c & 2047) + (size_t)q * CL * HID;
  float h = 0.0f, p = 1.0f;
#pragma unroll 4
  for (int t = 0; t < CL; ++t) {
    size_t idx = base + (size_t)t * HID;
    float f = F[idx];
    float iv = IO[idx];
    h = fmaf(f, h, iv - iv * f);  // f*h + silu_i*(1-f)
    p *= f;
    IO[idx] = h;
  }
  P[q * NCH + c] = p;
  H[q * NCH + c] = h;
}

__global__ __launch_bounds__(256) void scan2_kernel(
    const float* __restrict__ P, const float* __restrict__ H,
    float* __restrict__ Ini) {
  int c = blockIdx.x * 256 + threadIdx.x;
  float carry = 0.0f;
#pragma unroll
  for (int q = 0; q < NC; ++q) {
    float pq = P[q * NCH + c];  // read before in-place write
    float hq = H[q * NCH + c];
    Ini[q * NCH + c] = carry;
    carry = fmaf(pq, carry, hq);
  }
}

__global__ __launch_bounds__(256) void scan3_kernel(
    const float* __restrict__ F, const float* __restrict__ Ini,
    float* __restrict__ IO) {
  int c = blockIdx.x * 256 + threadIdx.x;
  int q = blockIdx.y + 1;
  float h0 = Ini[q * NCH + c];
  if (h0 == 0.0f) return;
  size_t base =
      (size_t)(c >> 11) * TT * HID + (c & 2047) + (size_t)q * CL * HID;
  float p = 1.0f;
#pragma unroll 4
  for (int t = 0; t < CL; ++t) {
    size_t idx = base + (size_t)t * HID;
    p *= F[idx];
    IO[idx] = fmaf(p, h0, IO[idx]);
  }
}

// ---------------- K6: fused  o=rms(g)*o*sigm(o)  ->  rms(o,n_o)+quant -----
__global__ __launch_bounds__(256) void combine_quant_kernel(
    const float* __restrict__ G, const float* __restrict__ gnw,
    const float* __restrict__ O, const float* __restrict__ nw,
    i8* __restrict__ Xq, float* __restrict__ inv_s) {
  int tok = blockIdx.x;
  int tid = threadIdx.x;
  int c0 = tid * 8;
  const float* grow = G + (size_t)tok * HID;
  const float* orow = O + (size_t)tok * HID;
  float g[8], o[8];
  *(float4*)&g[0] = *(const float4*)&grow[c0];
  *(float4*)&g[4] = *(const float4*)&grow[c0 + 4];
  *(float4*)&o[0] = *(const float4*)&orow[c0];
  *(float4*)&o[4] = *(const float4*)&orow[c0 + 4];
  __shared__ float sh[4];
  float ss = 0.0f;
#pragma unroll
  for (int j = 0; j < 8; ++j) ss += g[j] * g[j];
  float v = wred_sum(ss);
  if ((tid & 63) == 0) sh[tid >> 6] = v;
  __syncthreads();
  float tot = (sh[0] + sh[1]) + (sh[2] + sh[3]);
  float rstd_g = (float)(1.0 / sqrt((double)(tot * (1.0f / HID)) + 1e-5));
  float on[8];
  float ss2 = 0.0f;
#pragma unroll
  for (int j = 0; j < 8; ++j) {
    on[j] = g[j] * rstd_g * gnw[c0 + j] * o[j] * sigm(o[j]);
    ss2 += on[j] * on[j];
  }
  __syncthreads();
  v = wred_sum(ss2);
  if ((tid & 63) == 0) sh[tid >> 6] = v;
  __syncthreads();
  float tot2 = (sh[0] + sh[1]) + (sh[2] + sh[3]);
  float rstd_o = (float)(1.0 / sqrt((double)(tot2 * (1.0f / HID)) + 1e-8));
  float y[8];
  float amax = 0.0f;
#pragma unroll
  for (int j = 0; j < 8; ++j) {
    y[j] = on[j] * rstd_o * nw[c0 + j];
    amax = fmaxf(amax, fabsf(y[j]));
  }
  __syncthreads();
  v = wred_max(amax);
  if ((tid & 63) == 0) sh[tid >> 6] = v;
  __syncthreads();
  float am = fmaxf(fmaxf(fmaxf(sh[0], sh[1]), fmaxf(sh[2], sh[3])), 1e-5f);
  float s = 127.0f / am;
  int qi[8];
#pragma unroll
  for (int j = 0; j < 8; ++j) {
    float qq = rintf(y[j] * s);
    qq = fminf(fmaxf(qq, -128.0f), 127.0f);
    qi[j] = (int)qq;
  }
  *(int2*)&Xq[(size_t)tok * HID + c0] = make_int2(pack8(qi), pack8(qi + 4));
  if (tid == 0) inv_s[tok] = am * (1.0f / 127.0f);
}

extern "C" void kernel_launch(void* const* d_in, const int* in_sizes, int n_in,
                              void* d_out, int out_size, void* d_ws,
                              size_t ws_size, hipStream_t stream) {
  const float* hs = (const float*)d_in[0];
  const float* w_i = (const float*)d_in[1];
  const float* w_f = (const float*)d_in[2];
  const float* w_g = (const float*)d_in[3];
  const float* w_o = (const float*)d_in[4];
  const float* n_i = (const float*)d_in[5];
  const float* n_f = (const float*)d_in[6];
  const float* n_g = (const float*)d_in[7];
  const float* n_o = (const float*)d_in[8];
  const float* gn_w = (const float*)d_in[9];
  float* Out = (float*)d_out;

  char* ws = (char*)d_ws;
  // WQ0 @0 4.2M | WQ1 @4.2M 4.2M | XQ0 @8.4M | XQ1 @16.8M | F @25.2M 33.5M
  // invs0/invs1/wsum/scanP(=Ini)/scanH ; total 59.8MB
  i8* WQ0 = (i8*)ws;
  i8* WQ1 = (i8*)(ws + 4194304);
  i8* XQ0 = (i8*)(ws + 8388608);
  i8* XQ1 = (i8*)(ws + 16777216);
  float* F = (float*)(ws + 25165824);
  float* G = F;  // alias: F dead after scan3, G computed after
  float* invs0 = (float*)(ws + 58720256);
  float* invs1 = (float*)(ws + 58736640);
  double* wsum = (double*)(ws + 58753024);
  float* scanP = (float*)(ws + 58754048);  // also Ini (in-place scan2)
  float* scanH = (float*)(ws + 59278336);

  hipMemsetAsync(wsum, 0, 4 * sizeof(double), stream);
  // wsum order: 0=i, 1=f, 2=g, 3=o
  absmean_kernel<<<2048, 256, 0, stream>>>(w_i, w_f, w_g, w_o, wsum);

  // quantize w_f -> WQ0, w_i -> WQ1
  wquant2_kernel<<<4096, 256, 0, stream>>>(w_f, w_i, wsum, 1, 0, WQ0, WQ1);
  // one pass over hs produces both f- and i- quantized activations
  rmsquant2_kernel<<<TOKENS, 256, 0, stream>>>(hs, n_f, n_i, XQ0, XQ1, invs0,
                                               invs1);

  // merged: F = sigmoid(hs*Wf), Out = silu(hs*Wi)   (1024 blocks)
  gemmr_kernel<<<1024, 256, 0, stream>>>(XQ0, XQ1, WQ0, WQ1, invs0, invs1,
                                         wsum, 1, 0, F, Out, 0, 1);

  // quantize w_g -> WQ0, w_o -> WQ1 (f/i weights dead after fi-GEMM)
  wquant2_kernel<<<4096, 256, 0, stream>>>(w_g, w_o, wsum, 2, 3, WQ0, WQ1);
  // g activations reuse XQ0/invs0
  rmsquant_kernel<<<TOKENS, 256, 0, stream>>>(hs, n_g, XQ0, invs0);

  // scan: h_t = f_t*h + silu_i_t*(1-f_t), in-place in Out
  scan1_kernel<<<dim3(NCH / 256, NC), 256, 0, stream>>>(F, Out, scanP, scanH);
  scan2_kernel<<<NCH / 256, 256, 0, stream>>>(scanP, scanH, scanP);
  scan3_kernel<<<dim3(NCH / 256, NC - 1), 256, 0, stream>>>(F, scanP, Out);

  // g = bitlinear(hs, w_g, n_g) -> G (aliases F)
  gemmr_kernel<<<512, 256, 0, stream>>>(XQ0, XQ0, WQ0, WQ0, invs0, invs0, wsum,
                                        2, 2, G, G, 2, 2);

  // fused: o = rms(g)*o*sigm(o); then rms(o, n_o) + act-quant -> XQ1
  combine_quant_kernel<<<TOKENS, 256, 0, stream>>>(G, gn_w, Out, n_o, XQ1,
                                                   invs1);

  // out = bitlinear(o, w_o, n_o)
  gemmr_kernel<<<512, 256, 0, stream>>>(XQ1, XQ1, WQ1, WQ1, invs1, invs1, wsum,
                                        3, 3, Out, Out, 2, 2);
}

// Round 8
// 236.808 us; speedup vs baseline: 1.6622x; 1.6622x over previous
//
#include <hip/hip_runtime.h>
#include <math.h>

#define HID 2048
#define TOKENS 4096   // B*T
#define TT 2048       // T
#define NCH 4096      // B*HID independent scan channels
#define NC 32         // scan chunks along T
#define CL 64         // chunk length = TT/NC
#define WELEM 4194304 // 2048*2048

typedef unsigned short u16;
typedef signed char i8;
typedef int i32x4 __attribute__((ext_vector_type(4)));

__device__ inline float sigm(float x) { return 1.0f / (1.0f + expf(-x)); }

__device__ inline float wred_sum(float v) {
#pragma unroll
  for (int o = 32; o > 0; o >>= 1) v += __shfl_down(v, o);
  return v;
}
__device__ inline float wred_max(float v) {
#pragma unroll
  for (int o = 32; o > 0; o >>= 1) v = fmaxf(v, __shfl_down(v, o));
  return v;
}
__device__ inline double wred_sumd(double v) {
#pragma unroll
  for (int o = 32; o > 0; o >>= 1) v += __shfl_down(v, o);
  return v;
}

// async global->LDS, 16B per lane; LDS dest = wave-uniform base + lane*16
__device__ __forceinline__ void gl_lds16(const void* g, void* l) {
  __builtin_amdgcn_global_load_lds(
      (__attribute__((address_space(1))) void*)(void*)g,
      (__attribute__((address_space(3))) void*)l, 16, 0, 0);
}

__device__ __forceinline__ int pack8(const int* qi) {
  return (qi[0] & 255) | ((qi[1] & 255) << 8) | ((qi[2] & 255) << 16)
       | ((qi[3] & 255) << 24);
}

// ---------------- K1: mean(|w|) for the 4 weights, f64 accumulation -------
__global__ __launch_bounds__(256) void absmean_kernel(
    const float* __restrict__ w0, const float* __restrict__ w1,
    const float* __restrict__ w2, const float* __restrict__ w3,
    double* __restrict__ wsum) {
  int widx = blockIdx.x >> 9;
  int blk = blockIdx.x & 511;
  const float* w = widx == 0 ? w0 : widx == 1 ? w1 : widx == 2 ? w2 : w3;
  size_t base = (size_t)blk * 8192;
  double acc = 0.0;
#pragma unroll
  for (int r = 0; r < 8; ++r) {
    float4 v = *(const float4*)&w[base + (size_t)(r * 256 + threadIdx.x) * 4];
    acc += (double)fabsf(v.x) + (double)fabsf(v.y) + (double)fabsf(v.z) +
           (double)fabsf(v.w);
  }
  acc = wred_sumd(acc);
  __shared__ double sh[4];
  int tid = threadIdx.x;
  if ((tid & 63) == 0) sh[tid >> 6] = acc;
  __syncthreads();
  if (tid == 0) atomicAdd(&wsum[widx], (sh[0] + sh[1]) + (sh[2] + sh[3]));
}

// ---------------- K2: ternary-quantize TWO weight matrices to int8 --------
__global__ __launch_bounds__(256) void wquant2_kernel(
    const float* __restrict__ wA, const float* __restrict__ wB,
    const double* __restrict__ wsum, int widxA, int widxB,
    i8* __restrict__ wqA, i8* __restrict__ wqB) {
  int sel = blockIdx.x >> 11;  // 0: A, 1: B
  int blk = blockIdx.x & 2047;
  const float* w = sel ? wB : wA;
  i8* wq = sel ? wqB : wqA;
  int widx = sel ? widxB : widxA;
  double mean = wsum[widx] * (1.0 / (double)WELEM);
  float s = (float)(1.0 / fmax(mean, 1e-5));
  size_t base = (size_t)blk * 2048 + (size_t)threadIdx.x * 8;
  float4 va = *(const float4*)&w[base];
  float4 vb = *(const float4*)&w[base + 4];
  float vv[8] = {va.x, va.y, va.z, va.w, vb.x, vb.y, vb.z, vb.w};
  int qi[8];
#pragma unroll
  for (int j = 0; j < 8; ++j) {
    float q1 = rintf(vv[j] * s);
    q1 = fminf(fmaxf(q1, -1.0f), 1.0f);
    qi[j] = (int)q1;
  }
  *(int2*)&wq[base] = make_int2(pack8(qi), pack8(qi + 4));
}

// ---------------- K3: per-token RMSNorm + 8-bit fake quant -> int8 --------
__global__ __launch_bounds__(256) void rmsquant_kernel(
    const float* __restrict__ X, const float* __restrict__ nw,
    i8* __restrict__ Xq, float* __restrict__ inv_s) {
  int tok = blockIdx.x;
  int tid = threadIdx.x;
  const float* xrow = X + (size_t)tok * HID;
  int c0 = tid * 8;
  float x[8];
  *(float4*)&x[0] = *(const float4*)&xrow[c0];
  *(float4*)&x[4] = *(const float4*)&xrow[c0 + 4];
  float ss = 0.0f;
#pragma unroll
  for (int j = 0; j < 8; ++j) ss += x[j] * x[j];
  __shared__ float sh[4];
  float v = wred_sum(ss);
  if ((tid & 63) == 0) sh[tid >> 6] = v;
  __syncthreads();
  float tot = (sh[0] + sh[1]) + (sh[2] + sh[3]);
  float rstd = (float)(1.0 / sqrt((double)(tot * (1.0f / HID)) + 1e-8));
  float y[8];
  float amax = 0.0f;
#pragma unroll
  for (int j = 0; j < 8; ++j) {
    y[j] = x[j] * rstd * nw[c0 + j];
    amax = fmaxf(amax, fabsf(y[j]));
  }
  __syncthreads();
  v = wred_max(amax);
  if ((tid & 63) == 0) sh[tid >> 6] = v;
  __syncthreads();
  float am = fmaxf(fmaxf(fmaxf(sh[0], sh[1]), fmaxf(sh[2], sh[3])), 1e-5f);
  float s = 127.0f / am;
  int qi[8];
#pragma unroll
  for (int j = 0; j < 8; ++j) {
    float qq = rintf(y[j] * s);
    qq = fminf(fmaxf(qq, -128.0f), 127.0f);
    qi[j] = (int)qq;
  }
  *(int2*)&Xq[(size_t)tok * HID + c0] = make_int2(pack8(qi), pack8(qi + 4));
  if (tid == 0) inv_s[tok] = am * (1.0f / 127.0f);
}

// ---------------- K3b: fused dual RMSNorm+quant (shares x and sum-sq) -----
__global__ __launch_bounds__(256) void rmsquant2_kernel(
    const float* __restrict__ X, const float* __restrict__ nw0,
    const float* __restrict__ nw1, i8* __restrict__ Xq0, i8* __restrict__ Xq1,
    float* __restrict__ inv0, float* __restrict__ inv1) {
  int tok = blockIdx.x;
  int tid = threadIdx.x;
  const float* xrow = X + (size_t)tok * HID;
  int c0 = tid * 8;
  float x[8];
  *(float4*)&x[0] = *(const float4*)&xrow[c0];
  *(float4*)&x[4] = *(const float4*)&xrow[c0 + 4];
  float ss = 0.0f;
#pragma unroll
  for (int j = 0; j < 8; ++j) ss += x[j] * x[j];
  __shared__ float sh[4];
  float v = wred_sum(ss);
  if ((tid & 63) == 0) sh[tid >> 6] = v;
  __syncthreads();
  float tot = (sh[0] + sh[1]) + (sh[2] + sh[3]);
  float rstd = (float)(1.0 / sqrt((double)(tot * (1.0f / HID)) + 1e-8));
#pragma unroll
  for (int pass = 0; pass < 2; ++pass) {
    const float* nw = pass == 0 ? nw0 : nw1;
    i8* Xq = pass == 0 ? Xq0 : Xq1;
    float* inv_s = pass == 0 ? inv0 : inv1;
    float y[8];
    float amax = 0.0f;
#pragma unroll
    for (int j = 0; j < 8; ++j) {
      y[j] = x[j] * rstd * nw[c0 + j];
      amax = fmaxf(amax, fabsf(y[j]));
    }
    __syncthreads();
    float vv = wred_max(amax);
    if ((tid & 63) == 0) sh[tid >> 6] = vv;
    __syncthreads();
    float am = fmaxf(fmaxf(fmaxf(sh[0], sh[1]), fmaxf(sh[2], sh[3])), 1e-5f);
    float s = 127.0f / am;
    int qi[8];
#pragma unroll
    for (int j = 0; j < 8; ++j) {
      float qq = rintf(y[j] * s);
      qq = fminf(fmaxf(qq, -128.0f), 127.0f);
      qi[j] = (int)qq;
    }
    *(int2*)&Xq[(size_t)tok * HID + c0] = make_int2(pack8(qi), pack8(qi + 4));
    if (tid == 0) inv_s[tok] = am * (1.0f / 127.0f);
  }
}

// ---------------- K4: i8 MFMA GEMM, 8 waves, BK=128 (16 barriers) ---------
// out[m,n] = sum_k A[m,k]*W[n,k]; i32 accumulate (exact; |acc| <= 2^25).
// mode 0: sigmoid(v); 1: v*sigm(v) (silu); 2: v
// Block 128x128, 8 waves: wave (wm=wave>>2 in{0,1}, wn=wave&3) owns 64x32.
// LDS per buf: A 128x128B (16KB) + B 16KB; dbuf = 64KB -> 2 blocks/CU.
// Swizzle (8 slots of 16B per 128B row): physical slot = logical ^ (row&7),
// applied inverse on the global source (linear gl_lds dest), forward on
// ds_read. Reads: 2 lanes/bank max (free). Source stays fully coalesced.
__global__ __launch_bounds__(512) void gemm8_kernel(
    const i8* __restrict__ Aq, const i8* __restrict__ Wq,
    const float* __restrict__ inv_s, const double* __restrict__ wsum, int widx,
    float* __restrict__ Out, int mode) {
  const int tid = threadIdx.x;
  // XCD-aware bijective swizzle: 512 blocks, 64 consecutive per XCD
  const int lid = blockIdx.x;
  const int swz = (lid & 7) * 64 + (lid >> 3);
  const int n0 = (swz & 15) * 128;  // 16 n-tiles (HID/128)
  const int m0 = (swz >> 4) * 128;  // 32 m-tiles (TOKENS/128)

  __shared__ __align__(16) i8 As[2][16384];
  __shared__ __align__(16) i8 Bs[2][16384];
  float wscale = (float)fmax(wsum[widx] * (1.0 / (double)WELEM), 1e-5);

  const int wave = tid >> 6, lane = tid & 63;
  const int wm = wave >> 2;                 // M half
  const int wn = wave & 3;                  // N quarter
  const int lrow = lane & 15;
  const int ksel = lane >> 4;               // 16B quarter within 64B half
  const int rsw = lrow & 7;                 // read-side swizzle key
  const int srow8 = lane >> 3;              // staging row within 8-row chunk
  const int scol = ((lane & 7) ^ srow8) << 4;  // inverse-swizzled byte col

  const i8* Ab = Aq + (size_t)m0 * HID;
  const i8* Wb = Wq + (size_t)n0 * HID;

  i32x4 acc[4][2];
#pragma unroll
  for (int i = 0; i < 4; ++i)
#pragma unroll
    for (int j = 0; j < 2; ++j)
#pragma unroll
      for (int r = 0; r < 4; ++r) acc[i][j][r] = 0;

  // staging: 16 chunks of 8 rows x 128B per matrix; 2 A + 2 B per wave
#define STAGE(buf, k0)                                                      \
  {                                                                         \
    _Pragma("unroll") for (int c = 0; c < 2; ++c) {                         \
      int chunk = wave * 2 + c;                                             \
      int row = chunk * 8 + srow8;                                          \
      gl_lds16(&Ab[(size_t)row * HID + (k0) + scol], &As[buf][chunk * 1024]); \
      gl_lds16(&Wb[(size_t)row * HID + (k0) + scol], &Bs[buf][chunk * 1024]); \
    }                                                                       \
  }

  const int NT = HID / 128;  // 16 K-steps
  STAGE(0, 0)
  __syncthreads();
  int cur = 0;
  for (int kt = 0; kt < NT; ++kt) {
    if (kt + 1 < NT) STAGE(cur ^ 1, (kt + 1) * 128)
    i32x4 af[4][2], bfr[2][2];
#pragma unroll
    for (int i = 0; i < 4; ++i) {
      int ra = wm * 64 + i * 16 + lrow;
#pragma unroll
      for (int kk = 0; kk < 2; ++kk) {
        int phys = ((kk << 2) | ksel) ^ rsw;
        af[i][kk] = *(const i32x4*)&As[cur][ra * 128 + phys * 16];
      }
    }
#pragma unroll
    for (int j = 0; j < 2; ++j) {
      int rb = wn * 32 + j * 16 + lrow;
#pragma unroll
      for (int kk = 0; kk < 2; ++kk) {
        int phys = ((kk << 2) | ksel) ^ rsw;
        bfr[j][kk] = *(const i32x4*)&Bs[cur][rb * 128 + phys * 16];
      }
    }
    __builtin_amdgcn_s_setprio(1);
#pragma unroll
    for (int kk = 0; kk < 2; ++kk)
#pragma unroll
      for (int i = 0; i < 4; ++i)
#pragma unroll
        for (int j = 0; j < 2; ++j)
          acc[i][j] = __builtin_amdgcn_mfma_i32_16x16x64_i8(
              af[i][kk], bfr[j][kk], acc[i][j], 0, 0, 0);
    __builtin_amdgcn_s_setprio(0);
    __syncthreads();  // drains prefetch vmcnt + protects LDS reuse
    cur ^= 1;
  }
#undef STAGE

#pragma unroll
  for (int i = 0; i < 4; ++i) {
    int rbase = m0 + wm * 64 + i * 16 + (lane >> 4) * 4;
#pragma unroll
    for (int j = 0; j < 2; ++j) {
      int col = n0 + wn * 32 + j * 16 + lrow;
#pragma unroll
      for (int r = 0; r < 4; ++r) {
        int row = rbase + r;
        float v = (float)acc[i][j][r] * inv_s[row] * wscale;
        size_t oidx = (size_t)row * HID + col;
        if (mode == 0) {
          Out[oidx] = sigm(v);
        } else if (mode == 1) {
          Out[oidx] = v * sigm(v);
        } else {
          Out[oidx] = v;
        }
      }
    }
  }
}

// ---------------- K5: chunked parallel scan h = f*h + silu_i*(1-f) --------
__global__ __launch_bounds__(256) void scan1_kernel(
    const float* __restrict__ F, float* __restrict__ IO, float* __restrict__ P,
    float* __restrict__ H) {
  int c = blockIdx.x * 256 + threadIdx.x;
  int q = blockIdx.y;
  size_t base =
      (size_t)(c >> 11) * TT * HID + (c & 2047) + (size_t)q * CL * HID;
  float h = 0.0f, p = 1.0f;
#pragma unroll 4
  for (int t = 0; t < CL; ++t) {
    size_t idx = base + (size_t)t * HID;
    float f = F[idx];
    float iv = IO[idx];
    h = fmaf(f, h, iv - iv * f);  // f*h + silu_i*(1-f)
    p *= f;
    IO[idx] = h;
  }
  P[q * NCH + c] = p;
  H[q * NCH + c] = h;
}

__global__ __launch_bounds__(256) void scan2_kernel(
    const float* __restrict__ P, const float* __restrict__ H,
    float* __restrict__ Ini) {
  int c = blockIdx.x * 256 + threadIdx.x;
  float carry = 0.0f;
#pragma unroll
  for (int q = 0; q < NC; ++q) {
    float pq = P[q * NCH + c];  // read before in-place write
    float hq = H[q * NCH + c];
    Ini[q * NCH + c] = carry;
    carry = fmaf(pq, carry, hq);
  }
}

__global__ __launch_bounds__(256) void scan3_kernel(
    const float* __restrict__ F, const float* __restrict__ Ini,
    float* __restrict__ IO) {
  int c = blockIdx.x * 256 + threadIdx.x;
  int q = blockIdx.y + 1;
  float h0 = Ini[q * NCH + c];
  if (h0 == 0.0f) return;
  size_t base =
      (size_t)(c >> 11) * TT * HID + (c & 2047) + (size_t)q * CL * HID;
  float p = 1.0f;
#pragma unroll 4
  for (int t = 0; t < CL; ++t) {
    size_t idx = base + (size_t)t * HID;
    p *= F[idx];
    IO[idx] = fmaf(p, h0, IO[idx]);
  }
}

// ---------------- K6: fused  o=rms(g)*o*sigm(o)  ->  rms(o,n_o)+quant -----
__global__ __launch_bounds__(256) void combine_quant_kernel(
    const float* __restrict__ G, const float* __restrict__ gnw,
    const float* __restrict__ O, const float* __restrict__ nw,
    i8* __restrict__ Xq, float* __restrict__ inv_s) {
  int tok = blockIdx.x;
  int tid = threadIdx.x;
  int c0 = tid * 8;
  const float* grow = G + (size_t)tok * HID;
  const float* orow = O + (size_t)tok * HID;
  float g[8], o[8];
  *(float4*)&g[0] = *(const float4*)&grow[c0];
  *(float4*)&g[4] = *(const float4*)&grow[c0 + 4];
  *(float4*)&o[0] = *(const float4*)&orow[c0];
  *(float4*)&o[4] = *(const float4*)&orow[c0 + 4];
  __shared__ float sh[4];
  float ss = 0.0f;
#pragma unroll
  for (int j = 0; j < 8; ++j) ss += g[j] * g[j];
  float v = wred_sum(ss);
  if ((tid & 63) == 0) sh[tid >> 6] = v;
  __syncthreads();
  float tot = (sh[0] + sh[1]) + (sh[2] + sh[3]);
  float rstd_g = (float)(1.0 / sqrt((double)(tot * (1.0f / HID)) + 1e-5));
  float on[8];
  float ss2 = 0.0f;
#pragma unroll
  for (int j = 0; j < 8; ++j) {
    on[j] = g[j] * rstd_g * gnw[c0 + j] * o[j] * sigm(o[j]);
    ss2 += on[j] * on[j];
  }
  __syncthreads();
  v = wred_sum(ss2);
  if ((tid & 63) == 0) sh[tid >> 6] = v;
  __syncthreads();
  float tot2 = (sh[0] + sh[1]) + (sh[2] + sh[3]);
  float rstd_o = (float)(1.0 / sqrt((double)(tot2 * (1.0f / HID)) + 1e-8));
  float y[8];
  float amax = 0.0f;
#pragma unroll
  for (int j = 0; j < 8; ++j) {
    y[j] = on[j] * rstd_o * nw[c0 + j];
    amax = fmaxf(amax, fabsf(y[j]));
  }
  __syncthreads();
  v = wred_max(amax);
  if ((tid & 63) == 0) sh[tid >> 6] = v;
  __syncthreads();
  float am = fmaxf(fmaxf(fmaxf(sh[0], sh[1]), fmaxf(sh[2], sh[3])), 1e-5f);
  float s = 127.0f / am;
  int qi[8];
#pragma unroll
  for (int j = 0; j < 8; ++j) {
    float qq = rintf(y[j] * s);
    qq = fminf(fmaxf(qq, -128.0f), 127.0f);
    qi[j] = (int)qq;
  }
  *(int2*)&Xq[(size_t)tok * HID + c0] = make_int2(pack8(qi), pack8(qi + 4));
  if (tid == 0) inv_s[tok] = am * (1.0f / 127.0f);
}

extern "C" void kernel_launch(void* const* d_in, const int* in_sizes, int n_in,
                              void* d_out, int out_size, void* d_ws,
                              size_t ws_size, hipStream_t stream) {
  const float* hs = (const float*)d_in[0];
  const float* w_i = (const float*)d_in[1];
  const float* w_f = (const float*)d_in[2];
  const float* w_g = (const float*)d_in[3];
  const float* w_o = (const float*)d_in[4];
  const float* n_i = (const float*)d_in[5];
  const float* n_f = (const float*)d_in[6];
  const float* n_g = (const float*)d_in[7];
  const float* n_o = (const float*)d_in[8];
  const float* gn_w = (const float*)d_in[9];
  float* Out = (float*)d_out;

  char* ws = (char*)d_ws;
  // WQ0 @0 4.2M | WQ1 @4.2M 4.2M | XQ0 @8.4M | XQ1 @16.8M | F @25.2M 33.5M
  // invs0/invs1/wsum/scanP(=Ini)/scanH ; total 59.8MB
  i8* WQ0 = (i8*)ws;
  i8* WQ1 = (i8*)(ws + 4194304);
  i8* XQ0 = (i8*)(ws + 8388608);
  i8* XQ1 = (i8*)(ws + 16777216);
  float* F = (float*)(ws + 25165824);
  float* G = F;  // alias: F dead after scan3, G computed after
  float* invs0 = (float*)(ws + 58720256);
  float* invs1 = (float*)(ws + 58736640);
  double* wsum = (double*)(ws + 58753024);
  float* scanP = (float*)(ws + 58754048);  // also Ini (in-place scan2)
  float* scanH = (float*)(ws + 59278336);

  hipMemsetAsync(wsum, 0, 4 * sizeof(double), stream);
  // wsum order: 0=i, 1=f, 2=g, 3=o
  absmean_kernel<<<2048, 256, 0, stream>>>(w_i, w_f, w_g, w_o, wsum);

  // quantize w_f -> WQ0, w_i -> WQ1
  wquant2_kernel<<<4096, 256, 0, stream>>>(w_f, w_i, wsum, 1, 0, WQ0, WQ1);
  // one pass over hs produces both f- and i- quantized activations
  rmsquant2_kernel<<<TOKENS, 256, 0, stream>>>(hs, n_f, n_i, XQ0, XQ1, invs0,
                                               invs1);

  // F = sigmoid(hs*Wf); Out = silu(hs*Wi)  (separate 512-block launches)
  gemm8_kernel<<<512, 512, 0, stream>>>(XQ0, WQ0, invs0, wsum, 1, F, 0);
  gemm8_kernel<<<512, 512, 0, stream>>>(XQ1, WQ1, invs1, wsum, 0, Out, 1);

  // quantize w_g -> WQ0, w_o -> WQ1 (f/i weights dead after their GEMMs)
  wquant2_kernel<<<4096, 256, 0, stream>>>(w_g, w_o, wsum, 2, 3, WQ0, WQ1);
  // g activations reuse XQ0/invs0 (freed by f-GEMM)
  rmsquant_kernel<<<TOKENS, 256, 0, stream>>>(hs, n_g, XQ0, invs0);

  // scan: h_t = f_t*h + silu_i_t*(1-f_t), in-place in Out
  scan1_kernel<<<dim3(NCH / 256, NC), 256, 0, stream>>>(F, Out, scanP, scanH);
  scan2_kernel<<<NCH / 256, 256, 0, stream>>>(scanP, scanH, scanP);
  scan3_kernel<<<dim3(NCH / 256, NC - 1), 256, 0, stream>>>(F, scanP, Out);

  // g = bitlinear(hs, w_g, n_g) -> G (aliases F; F dead after scan3)
  gemm8_kernel<<<512, 512, 0, stream>>>(XQ0, WQ0, invs0, wsum, 2, G, 2);

  // fused: o = rms(g)*o*sigm(o); then rms(o, n_o) + act-quant -> XQ1
  combine_quant_kernel<<<TOKENS, 256, 0, stream>>>(G, gn_w, Out, n_o, XQ1,
                                                   invs1);

  // out = bitlinear(o, w_o, n_o)
  gemm8_kernel<<<512, 512, 0, stream>>>(XQ1, WQ1, invs1, wsum, 3, Out, 2);
}